// Round 1
// baseline (630.110 us; speedup 1.0000x reference)
//
#include <hip/hip_runtime.h>

#define NH 16
#define HD 64
#define BB 8
#define SS 1024
#define TD 1024
#define LP 68   // padded LDS row stride (floats); 68*4B = 272B keeps 16B alignment

// ---------------------------------------------------------------------------
// Kernel 1: per-head QKV projection.
// Grid: (S/64, NH, B), 256 threads. q is pre-scaled by 1/sqrt(HD).
// Outputs in [B, H, S, 64] layout for attention-kernel locality.
// ---------------------------------------------------------------------------
__global__ __launch_bounds__(256) void proj_kernel(
    const float* __restrict__ x,
    const float* __restrict__ Wq, const float* __restrict__ Wk, const float* __restrict__ Wv,
    const float* __restrict__ bq, const float* __restrict__ bk, const float* __restrict__ bv,
    float* __restrict__ qo, float* __restrict__ ko, float* __restrict__ vo)
{
    __shared__ float Xt[HD][LP];   // Xt[d][s] : x tile transposed (k-dim major)
    __shared__ float Wl[HD][LP];   // Wl[d][e]

    const int st = blockIdx.x;
    const int h  = blockIdx.y;
    const int b  = blockIdx.z;
    const int t  = threadIdx.x;
    const int s0 = st * 64;

    // load + transpose x tile: 64 tokens x 64 dims of head h
    {
        const int row = t >> 2;            // token 0..63
        const int cb  = (t & 3) << 2;      // 0,4,8,12
        const float* src = x + ((size_t)b * SS + s0 + row) * TD + h * HD;
        #pragma unroll
        for (int i = 0; i < 4; ++i) {
            const int c = cb + i * 16;
            const float4 v4 = *reinterpret_cast<const float4*>(src + c);
            Xt[c + 0][row] = v4.x;
            Xt[c + 1][row] = v4.y;
            Xt[c + 2][row] = v4.z;
            Xt[c + 3][row] = v4.w;
        }
    }

    const int ts = t >> 4, te = t & 15;
    const int r0 = ts << 2, e0 = te << 2;

    const float* Ws[3] = {Wq, Wk, Wv};
    const float* bs[3] = {bq, bk, bv};
    float*       os[3] = {qo, ko, vo};

    for (int tz = 0; tz < 3; ++tz) {
        __syncthreads();   // previous GEMM done reading Wl (and Xt visible, iter 0)
        {
            const int row = t >> 2;
            const int cb  = (t & 3) << 2;
            const float* src = Ws[tz] + ((size_t)h * HD + row) * HD;
            #pragma unroll
            for (int i = 0; i < 4; ++i) {
                const int c = cb + i * 16;
                *reinterpret_cast<float4*>(&Wl[row][c]) =
                    *reinterpret_cast<const float4*>(src + c);
            }
        }
        __syncthreads();

        float acc[4][4] = {};
        #pragma unroll 4
        for (int d = 0; d < HD; ++d) {
            const float4 xv = *reinterpret_cast<const float4*>(&Xt[d][r0]);
            const float4 wv = *reinterpret_cast<const float4*>(&Wl[d][e0]);
            acc[0][0] += xv.x * wv.x; acc[0][1] += xv.x * wv.y;
            acc[0][2] += xv.x * wv.z; acc[0][3] += xv.x * wv.w;
            acc[1][0] += xv.y * wv.x; acc[1][1] += xv.y * wv.y;
            acc[1][2] += xv.y * wv.z; acc[1][3] += xv.y * wv.w;
            acc[2][0] += xv.z * wv.x; acc[2][1] += xv.z * wv.y;
            acc[2][2] += xv.z * wv.z; acc[2][3] += xv.z * wv.w;
            acc[3][0] += xv.w * wv.x; acc[3][1] += xv.w * wv.y;
            acc[3][2] += xv.w * wv.z; acc[3][3] += xv.w * wv.w;
        }

        const float4 bv4 = *reinterpret_cast<const float4*>(bs[tz] + h * HD + e0);
        const float sc = (tz == 0) ? 0.125f : 1.0f;   // fold 1/sqrt(64) into q
        float* op = os[tz] + (((size_t)b * NH + h) * SS + s0 + r0) * HD + e0;
        #pragma unroll
        for (int i = 0; i < 4; ++i) {
            float4 o4;
            o4.x = (acc[i][0] + bv4.x) * sc;
            o4.y = (acc[i][1] + bv4.y) * sc;
            o4.z = (acc[i][2] + bv4.z) * sc;
            o4.w = (acc[i][3] + bv4.w) * sc;
            *reinterpret_cast<float4*>(op + (size_t)i * HD) = o4;
        }
    }
}

// ---------------------------------------------------------------------------
// Kernel 2: flash-style fused attention, fp32 vector ALU.
// One block = one (b, h, 64-query tile). 256 threads, 16x16 grid, 4x4 regs.
// ---------------------------------------------------------------------------
__global__ __launch_bounds__(256) void attn_kernel(
    const float* __restrict__ qin, const float* __restrict__ kin,
    const float* __restrict__ vin, float* __restrict__ out)
{
    __shared__ float Qt[HD][LP];   // Qt[d][q]
    __shared__ float KP[HD][LP];   // Kt[d][j] during QK^T, then Pt[j][q] for PV
    __shared__ float Vl[64][LP];   // V[j][e]

    // XCD-bijective swizzle: 2048 blocks = 8 XCDs * 256. Work id ordered
    // q-tile-fastest, so each XCD owns 16 consecutive (b,h) pairs -> K/V L2 hits.
    const int p  = blockIdx.x;
    const int id = (p & 7) * 256 + (p >> 3);
    const int st = id & 15;          // q tile
    const int pr = id >> 4;          // b*NH + h
    const int h  = pr & (NH - 1);
    const int b  = pr >> 4;

    const int t = threadIdx.x;
    const size_t base = (size_t)pr * SS * HD;
    const float* Q = qin + base + (size_t)st * 64 * HD;
    const float* K = kin + base;
    const float* V = vin + base;

    const int lrow = t >> 2;
    const int lcb  = (t & 3) << 2;

    // load + transpose Q tile (once)
    {
        const float* src = Q + lrow * HD;
        #pragma unroll
        for (int i = 0; i < 4; ++i) {
            const int c = lcb + i * 16;
            const float4 v4 = *reinterpret_cast<const float4*>(src + c);
            Qt[c + 0][lrow] = v4.x;
            Qt[c + 1][lrow] = v4.y;
            Qt[c + 2][lrow] = v4.z;
            Qt[c + 3][lrow] = v4.w;
        }
    }

    const int tq = t >> 4, tk = t & 15;
    const int q0 = tq << 2, j0 = tk << 2;

    float m[4] = {-3e38f, -3e38f, -3e38f, -3e38f};
    float l[4] = {0.f, 0.f, 0.f, 0.f};
    float o[4][4] = {};

    for (int kt = 0; kt < 16; ++kt) {
        __syncthreads();   // previous PV done; safe to overwrite KP/Vl (also Qt visible, iter 0)
        {
            const float* ks = K + (size_t)(kt * 64 + lrow) * HD;
            const float* vs = V + (size_t)(kt * 64 + lrow) * HD;
            #pragma unroll
            for (int i = 0; i < 4; ++i) {
                const int c = lcb + i * 16;
                const float4 k4 = *reinterpret_cast<const float4*>(ks + c);
                KP[c + 0][lrow] = k4.x;
                KP[c + 1][lrow] = k4.y;
                KP[c + 2][lrow] = k4.z;
                KP[c + 3][lrow] = k4.w;
                *reinterpret_cast<float4*>(&Vl[lrow][c]) =
                    *reinterpret_cast<const float4*>(vs + c);
            }
        }
        __syncthreads();

        // S = Q K^T (Q pre-scaled by 1/sqrt(d))
        float s[4][4] = {};
        #pragma unroll 4
        for (int d = 0; d < HD; ++d) {
            const float4 qv = *reinterpret_cast<const float4*>(&Qt[d][q0]);
            const float4 kv = *reinterpret_cast<const float4*>(&KP[d][j0]);
            s[0][0] += qv.x * kv.x; s[0][1] += qv.x * kv.y;
            s[0][2] += qv.x * kv.z; s[0][3] += qv.x * kv.w;
            s[1][0] += qv.y * kv.x; s[1][1] += qv.y * kv.y;
            s[1][2] += qv.y * kv.z; s[1][3] += qv.y * kv.w;
            s[2][0] += qv.z * kv.x; s[2][1] += qv.z * kv.y;
            s[2][2] += qv.z * kv.z; s[2][3] += qv.z * kv.w;
            s[3][0] += qv.w * kv.x; s[3][1] += qv.w * kv.y;
            s[3][2] += qv.w * kv.z; s[3][3] += qv.w * kv.w;
        }

        // online softmax; row group = 16 consecutive lanes (same tq)
        float rmax[4], psum[4], scal[4];
        #pragma unroll
        for (int i = 0; i < 4; ++i)
            rmax[i] = fmaxf(fmaxf(s[i][0], s[i][1]), fmaxf(s[i][2], s[i][3]));
        #pragma unroll
        for (int off = 8; off >= 1; off >>= 1) {
            #pragma unroll
            for (int i = 0; i < 4; ++i)
                rmax[i] = fmaxf(rmax[i], __shfl_xor(rmax[i], off, 16));
        }

        float pp[4][4];
        #pragma unroll
        for (int i = 0; i < 4; ++i) {
            const float nm = fmaxf(m[i], rmax[i]);
            scal[i] = __expf(m[i] - nm);
            m[i] = nm;
            pp[i][0] = __expf(s[i][0] - nm);
            pp[i][1] = __expf(s[i][1] - nm);
            pp[i][2] = __expf(s[i][2] - nm);
            pp[i][3] = __expf(s[i][3] - nm);
            psum[i] = pp[i][0] + pp[i][1] + pp[i][2] + pp[i][3];
        }
        #pragma unroll
        for (int off = 8; off >= 1; off >>= 1) {
            #pragma unroll
            for (int i = 0; i < 4; ++i)
                psum[i] += __shfl_xor(psum[i], off, 16);
        }
        #pragma unroll
        for (int i = 0; i < 4; ++i) {
            l[i] = l[i] * scal[i] + psum[i];
            o[i][0] *= scal[i]; o[i][1] *= scal[i];
            o[i][2] *= scal[i]; o[i][3] *= scal[i];
        }

        __syncthreads();   // everyone done reading KP as Kt
        // store P transposed: Pt[j][q]
        #pragma unroll
        for (int j = 0; j < 4; ++j) {
            *reinterpret_cast<float4*>(&KP[j0 + j][q0]) =
                make_float4(pp[0][j], pp[1][j], pp[2][j], pp[3][j]);
        }
        __syncthreads();

        // O += P @ V  (thread's second index now = output dim e0 = j0)
        #pragma unroll 4
        for (int k = 0; k < 64; ++k) {
            const float4 pv = *reinterpret_cast<const float4*>(&KP[k][q0]);
            const float4 vv = *reinterpret_cast<const float4*>(&Vl[k][j0]);
            o[0][0] += pv.x * vv.x; o[0][1] += pv.x * vv.y;
            o[0][2] += pv.x * vv.z; o[0][3] += pv.x * vv.w;
            o[1][0] += pv.y * vv.x; o[1][1] += pv.y * vv.y;
            o[1][2] += pv.y * vv.z; o[1][3] += pv.y * vv.w;
            o[2][0] += pv.z * vv.x; o[2][1] += pv.z * vv.y;
            o[2][2] += pv.z * vv.z; o[2][3] += pv.z * vv.w;
            o[3][0] += pv.w * vv.x; o[3][1] += pv.w * vv.y;
            o[3][2] += pv.w * vv.z; o[3][3] += pv.w * vv.w;
        }
    }

    // epilogue: normalize and store [B,S,TD]
    float* op = out + ((size_t)b * SS + st * 64 + q0) * TD + h * HD + j0;
    #pragma unroll
    for (int i = 0; i < 4; ++i) {
        const float inv = 1.0f / l[i];
        *reinterpret_cast<float4*>(op + (size_t)i * TD) =
            make_float4(o[i][0] * inv, o[i][1] * inv, o[i][2] * inv, o[i][3] * inv);
    }
}

extern "C" void kernel_launch(void* const* d_in, const int* in_sizes, int n_in,
                              void* d_out, int out_size, void* d_ws, size_t ws_size,
                              hipStream_t stream) {
    const float* x  = (const float*)d_in[0];
    const float* Wq = (const float*)d_in[1];
    const float* Wk = (const float*)d_in[2];
    const float* Wv = (const float*)d_in[3];
    const float* bq = (const float*)d_in[4];
    const float* bk = (const float*)d_in[5];
    const float* bv = (const float*)d_in[6];
    float* out = (float*)d_out;

    const size_t per = (size_t)BB * NH * SS * HD;   // 8.39M floats = 32 MB
    float* q = (float*)d_ws;                        // needs 96 MB workspace total
    float* k = q + per;
    float* v = k + per;

    dim3 gp(SS / 64, NH, BB);
    proj_kernel<<<gp, dim3(256), 0, stream>>>(x, Wq, Wk, Wv, bq, bk, bv, q, k, v);

    attn_kernel<<<dim3(BB * NH * (SS / 64)), dim3(256), 0, stream>>>(q, k, v, out);
}

// Round 2
// 264.785 us; speedup vs baseline: 2.3797x; 2.3797x over previous
//
#include <hip/hip_runtime.h>
#include <stdint.h>

#define NH 16
#define HD 64
#define BB 8
#define SS 1024
#define TD 1024

typedef __attribute__((ext_vector_type(8))) short bf16x8;
typedef __attribute__((ext_vector_type(4))) float f32x4;

#define MFMA(a, b, c) __builtin_amdgcn_mfma_f32_16x16x32_bf16((a), (b), (c), 0, 0, 0)
// XOR swizzle: row-major [64][128B] tile, spreads 16B slots across banks per 8-row stripe
#define SW(r, c) (((r) << 7) + ((c) ^ (((r) & 7) << 4)))

__device__ __forceinline__ float asf(unsigned u) { return __builtin_bit_cast(float, u); }
__device__ __forceinline__ unsigned asu(float f) { return __builtin_bit_cast(unsigned, f); }

__device__ __forceinline__ unsigned cvtpk(float a, float b) {
    unsigned r;
    asm("v_cvt_pk_bf16_f32 %0, %1, %2" : "=v"(r) : "v"(a), "v"(b));
    return r;
}

struct HiLo { uint4 hi, lo; };
// split 8 fp32 -> 8 bf16 hi + 8 bf16 lo (lo = RTNE(x - hi))
__device__ __forceinline__ HiLo split8(float4 A, float4 B) {
    HiLo r;
    unsigned h0 = cvtpk(A.x, A.y), h1 = cvtpk(A.z, A.w);
    unsigned h2 = cvtpk(B.x, B.y), h3 = cvtpk(B.z, B.w);
    r.hi = make_uint4(h0, h1, h2, h3);
    float l0 = A.x - asf(h0 << 16), l1 = A.y - asf(h0 & 0xFFFF0000u);
    float l2 = A.z - asf(h1 << 16), l3 = A.w - asf(h1 & 0xFFFF0000u);
    float l4 = B.x - asf(h2 << 16), l5 = B.y - asf(h2 & 0xFFFF0000u);
    float l6 = B.z - asf(h3 << 16), l7 = B.w - asf(h3 & 0xFFFF0000u);
    r.lo = make_uint4(cvtpk(l0, l1), cvtpk(l2, l3), cvtpk(l4, l5), cvtpk(l6, l7));
    return r;
}

// max/sum over the 16-lane DPP row via row_ror 1,2,4,8 (VALU, not LDS pipe)
__device__ __forceinline__ float rowMax16(float x) {
    float y;
    y = asf((unsigned)__builtin_amdgcn_update_dpp(0, (int)asu(x), 0x121, 0xF, 0xF, true)); x = fmaxf(x, y);
    y = asf((unsigned)__builtin_amdgcn_update_dpp(0, (int)asu(x), 0x122, 0xF, 0xF, true)); x = fmaxf(x, y);
    y = asf((unsigned)__builtin_amdgcn_update_dpp(0, (int)asu(x), 0x124, 0xF, 0xF, true)); x = fmaxf(x, y);
    y = asf((unsigned)__builtin_amdgcn_update_dpp(0, (int)asu(x), 0x128, 0xF, 0xF, true)); x = fmaxf(x, y);
    return x;
}
__device__ __forceinline__ float rowSum16(float x) {
    float y;
    y = asf((unsigned)__builtin_amdgcn_update_dpp(0, (int)asu(x), 0x121, 0xF, 0xF, true)); x += y;
    y = asf((unsigned)__builtin_amdgcn_update_dpp(0, (int)asu(x), 0x122, 0xF, 0xF, true)); x += y;
    y = asf((unsigned)__builtin_amdgcn_update_dpp(0, (int)asu(x), 0x124, 0xF, 0xF, true)); x += y;
    y = asf((unsigned)__builtin_amdgcn_update_dpp(0, (int)asu(x), 0x128, 0xF, 0xF, true)); x += y;
    return x;
}

__device__ __forceinline__ f32x4 splat4(float v) { f32x4 r = {v, v, v, v}; return r; }
__device__ __forceinline__ f32x4 vmax4(f32x4 a, f32x4 b) {
    f32x4 r; r.x = fmaxf(a.x, b.x); r.y = fmaxf(a.y, b.y);
    r.z = fmaxf(a.z, b.z); r.w = fmaxf(a.w, b.w); return r;
}
__device__ __forceinline__ f32x4 vexp4(f32x4 a) {
    f32x4 r; r.x = __expf(a.x); r.y = __expf(a.y); r.z = __expf(a.z); r.w = __expf(a.w); return r;
}

// ---------------------------------------------------------------------------
// Kernel 1: per-head QKV projection (fp32), q pre-scaled by 1/sqrt(64).
// Outputs: q,k as [pair][S][64]; v TRANSPOSED as [pair][64][S].
// Grid (8, 16, 8) = 1024 blocks, 256 threads, 8x4 register tiles.
// ---------------------------------------------------------------------------
__global__ __launch_bounds__(256) void proj_kernel(
    const float* __restrict__ x,
    const float* __restrict__ Wq, const float* __restrict__ Wk, const float* __restrict__ Wv,
    const float* __restrict__ bq, const float* __restrict__ bk, const float* __restrict__ bv,
    float* __restrict__ qo, float* __restrict__ ko, float* __restrict__ vo)
{
    __shared__ float Xt[64][136];   // Xt[d][s], 128 tokens + pad
    __shared__ float Wl[64][68];    // Wl[d][e]

    const int stile = blockIdx.x;
    const int h = blockIdx.y, b = blockIdx.z;
    const int t = threadIdx.x;
    const int s0 = stile * 128;
    const int pair = b * NH + h;

    {   // stage + transpose x tile: 128 tokens x 64 dims of head h
        const int tok = t >> 1;
        const int dh = (t & 1) * 32;
        const float* src = x + ((size_t)b * SS + s0 + tok) * TD + h * HD + dh;
        #pragma unroll
        for (int i = 0; i < 8; ++i) {
            float4 v4 = *(const float4*)(src + i * 4);
            Xt[dh + i * 4 + 0][tok] = v4.x;
            Xt[dh + i * 4 + 1][tok] = v4.y;
            Xt[dh + i * 4 + 2][tok] = v4.z;
            Xt[dh + i * 4 + 3][tok] = v4.w;
        }
    }

    const float* Ws[3] = {Wq, Wk, Wv};
    const float* bs[3] = {bq, bk, bv};

    #pragma unroll 1
    for (int tz = 0; tz < 3; ++tz) {
        __syncthreads();    // previous GEMM done reading Wl
        {
            const int d = t >> 2, c0 = (t & 3) * 16;
            const float* src = Ws[tz] + ((size_t)h * HD + d) * HD + c0;
            #pragma unroll
            for (int i = 0; i < 4; ++i)
                *(float4*)(&Wl[d][c0 + i * 4]) = *(const float4*)(src + i * 4);
        }
        __syncthreads();

        const bool vmap = (tz == 2);                 // v uses transposed thread map
        const int sg = vmap ? (t & 15) : (t >> 4);
        const int eg = vmap ? (t >> 4) : (t & 15);
        const int e0 = eg * 4;
        const int sA = vmap ? sg * 4 : sg * 8;       // first 4-token group
        const int sB = vmap ? 64 + sg * 4 : sg * 8 + 4;  // second 4-token group

        float acc[8][4] = {};
        #pragma unroll 8
        for (int d = 0; d < 64; ++d) {
            const float4 x0 = *(const float4*)(&Xt[d][sA]);
            const float4 x1 = *(const float4*)(&Xt[d][sB]);
            const float4 wv = *(const float4*)(&Wl[d][e0]);
            const float xs[8] = {x0.x, x0.y, x0.z, x0.w, x1.x, x1.y, x1.z, x1.w};
            const float ww[4] = {wv.x, wv.y, wv.z, wv.w};
            #pragma unroll
            for (int i = 0; i < 8; ++i)
                #pragma unroll
                for (int j = 0; j < 4; ++j)
                    acc[i][j] += xs[i] * ww[j];
        }

        if (!vmap) {
            const float sc = (tz == 0) ? 0.125f : 1.0f;   // fold 1/sqrt(64) into q
            const float4 bb = *(const float4*)(bs[tz] + h * HD + e0);
            float* dst = (tz == 0 ? qo : ko) + ((size_t)pair * SS + s0 + sg * 8) * HD + e0;
            #pragma unroll
            for (int i = 0; i < 8; ++i) {
                float4 o4 = {(acc[i][0] + bb.x) * sc, (acc[i][1] + bb.y) * sc,
                             (acc[i][2] + bb.z) * sc, (acc[i][3] + bb.w) * sc};
                *(float4*)(dst + (size_t)i * HD) = o4;
            }
        } else {
            #pragma unroll
            for (int j = 0; j < 4; ++j) {
                const float bbv = bs[2][h * HD + e0 + j];
                float* dst = vo + ((size_t)pair * HD + e0 + j) * SS + s0;
                float4 o0 = {acc[0][j] + bbv, acc[1][j] + bbv, acc[2][j] + bbv, acc[3][j] + bbv};
                float4 o1 = {acc[4][j] + bbv, acc[5][j] + bbv, acc[6][j] + bbv, acc[7][j] + bbv};
                *(float4*)(dst + sA) = o0;
                *(float4*)(dst + sB) = o1;
            }
        }
    }
}

// ---------------------------------------------------------------------------
// Kernel 2: flash attention, bf16 MFMA with hi/lo split compensation.
// QBLK=128 (4 waves x 32 q-rows), KVBLK=64, 16 KV tiles.
// LDS 64KB: KH 0 | KL 8K | VH 16K | VL 24K | per-wave P at 32K + w*8K (PL +4K)
// ---------------------------------------------------------------------------
__global__ __launch_bounds__(256, 2) void attn_kernel(
    const float* __restrict__ qf, const float* __restrict__ kf,
    const float* __restrict__ vt, float* __restrict__ out)
{
    __shared__ uint4 lds4[65536 / 16];
    char* lds = (char*)lds4;

    // XCD-bijective swizzle: 1024 = 8 XCDs x 128; q-block fastest -> KV L2 reuse
    const int p = blockIdx.x;
    const int id = (p & 7) * 128 + (p >> 3);
    const int st = id & 7;            // q-block of 128 rows
    const int pr = id >> 3;           // b*NH + h
    const int h = pr & (NH - 1);
    const int b = pr >> 4;

    const int t = threadIdx.x;
    const int w = t >> 6;
    const int l = t & 63;
    const int l16 = l & 15;
    const int lg = l >> 4;

    const size_t pb = (size_t)pr * SS * HD;
    const int qrow0 = st * 128 + w * 32;

    // ---- Q fragments: global -> regs, hi/lo split (once) ----
    bf16x8 qh[2][2], qlo[2][2];
    #pragma unroll
    for (int qt = 0; qt < 2; ++qt)
        #pragma unroll
        for (int ch = 0; ch < 2; ++ch) {
            const float* src = qf + pb + (size_t)(qrow0 + qt * 16 + l16) * HD + ch * 32 + lg * 8;
            float4 A = *(const float4*)src;
            float4 B = *(const float4*)(src + 4);
            HiLo s8 = split8(A, B);
            qh[qt][ch] = __builtin_bit_cast(bf16x8, s8.hi);
            qlo[qt][ch] = __builtin_bit_cast(bf16x8, s8.lo);
        }

    // staging addresses: thread owns two 32B fp32 chunks of K and of V^T
    const char* kg = (const char*)(kf + pb) + t * 32;                  // + c*8192, + kt*16384
    const char* vg = (const char*)(vt + (size_t)pr * HD * SS) + ((t >> 3) * 4096 + (t & 7) * 32); // + c*131072, + kt*256
    const int jA = t >> 3, slA = t & 7;
    const int dK0 = SW(jA, slA * 16);
    const int dK1 = SW(jA + 32, slA * 16);
    const int dV0 = 16384 + SW(jA, slA * 16);
    const int dV1 = 16384 + SW(jA + 32, slA * 16);
    const int PH = 32768 + w * 8192;

    float4 ka0, ka1, kb0, kb1, va0, va1, vb0, vb1;
    auto issueLoads = [&](int kt) {
        const char* kp = kg + kt * 16384;
        ka0 = *(const float4*)kp;          ka1 = *(const float4*)(kp + 16);
        kb0 = *(const float4*)(kp + 8192); kb1 = *(const float4*)(kp + 8208);
        const char* vp = vg + kt * 256;
        va0 = *(const float4*)vp;            va1 = *(const float4*)(vp + 16);
        vb0 = *(const float4*)(vp + 131072); vb1 = *(const float4*)(vp + 131072 + 16);
    };
    auto writeStage = [&]() {
        HiLo k0 = split8(ka0, ka1);
        *(uint4*)(lds + dK0) = k0.hi; *(uint4*)(lds + dK0 + 8192) = k0.lo;
        HiLo k1 = split8(kb0, kb1);
        *(uint4*)(lds + dK1) = k1.hi; *(uint4*)(lds + dK1 + 8192) = k1.lo;
        HiLo v0 = split8(va0, va1);
        *(uint4*)(lds + dV0) = v0.hi; *(uint4*)(lds + dV0 + 8192) = v0.lo;
        HiLo v1 = split8(vb0, vb1);
        *(uint4*)(lds + dV1) = v1.hi; *(uint4*)(lds + dV1 + 8192) = v1.lo;
    };

    f32x4 m[2], ls[2], o[2][4];
    m[0] = m[1] = splat4(-3e38f);
    ls[0] = ls[1] = splat4(0.f);
    #pragma unroll
    for (int qt = 0; qt < 2; ++qt)
        #pragma unroll
        for (int et = 0; et < 4; ++et) o[qt][et] = splat4(0.f);

    issueLoads(0);

    for (int kt = 0; kt < 16; ++kt) {
        writeStage();
        __syncthreads();
        if (kt < 15) issueLoads(kt + 1);

        // ---- S = Q K^T (3-pass hi/lo) ----
        f32x4 s_[2][4];
        #pragma unroll
        for (int jt = 0; jt < 4; ++jt) {
            const int krow = jt * 16 + l16;
            bf16x8 kh0 = *(const bf16x8*)(lds + SW(krow, lg * 16));
            bf16x8 kh1 = *(const bf16x8*)(lds + SW(krow, 64 + lg * 16));
            bf16x8 kl0 = *(const bf16x8*)(lds + 8192 + SW(krow, lg * 16));
            bf16x8 kl1 = *(const bf16x8*)(lds + 8192 + SW(krow, 64 + lg * 16));
            #pragma unroll
            for (int qt = 0; qt < 2; ++qt) {
                f32x4 acc = splat4(0.f);
                acc = MFMA(qh[qt][0], kh0, acc);
                acc = MFMA(qh[qt][1], kh1, acc);
                acc = MFMA(qh[qt][0], kl0, acc);
                acc = MFMA(qh[qt][1], kl1, acc);
                acc = MFMA(qlo[qt][0], kh0, acc);
                acc = MFMA(qlo[qt][1], kh1, acc);
                s_[qt][jt] = acc;
            }
        }

        // ---- online softmax (rows replicated across 16-lane DPP rows) ----
        #pragma unroll
        for (int qt = 0; qt < 2; ++qt) {
            f32x4 mx = vmax4(vmax4(s_[qt][0], s_[qt][1]), vmax4(s_[qt][2], s_[qt][3]));
            f32x4 rmax;
            rmax.x = rowMax16(mx.x); rmax.y = rowMax16(mx.y);
            rmax.z = rowMax16(mx.z); rmax.w = rowMax16(mx.w);
            f32x4 nm = vmax4(m[qt], rmax);
            f32x4 sc = vexp4(m[qt] - nm);
            m[qt] = nm;
            ls[qt] *= sc;
            #pragma unroll
            for (int et = 0; et < 4; ++et) o[qt][et] *= sc;
            f32x4 ps = splat4(0.f);
            #pragma unroll
            for (int jt = 0; jt < 4; ++jt) {
                f32x4 pv = vexp4(s_[qt][jt] - nm);
                s_[qt][jt] = pv;
                ps += pv;
            }
            ps.x = rowSum16(ps.x); ps.y = rowSum16(ps.y);
            ps.z = rowSum16(ps.z); ps.w = rowSum16(ps.w);
            ls[qt] += ps;
            // write P (hi/lo) to this wave's LDS region
            #pragma unroll
            for (int jt = 0; jt < 4; ++jt) {
                const int col2 = (jt * 16 + l16) * 2;
                #pragma unroll
                for (int r = 0; r < 4; ++r) {
                    const int prow = qt * 16 + lg * 4 + r;
                    float pvv = s_[qt][jt][r];
                    unsigned hp = cvtpk(pvv, pvv);
                    *(short*)(lds + PH + SW(prow, col2)) = (short)(hp & 0xFFFF);
                    float lov = pvv - asf(hp << 16);
                    unsigned lp = cvtpk(lov, lov);
                    *(short*)(lds + PH + 4096 + SW(prow, col2)) = (short)(lp & 0xFFFF);
                }
            }
        }

        // ---- O += P V (3-pass hi/lo); same-wave P RAW is in-order ----
        bf16x8 pah[2][2], pal[2][2];
        #pragma unroll
        for (int qt = 0; qt < 2; ++qt)
            #pragma unroll
            for (int ch = 0; ch < 2; ++ch) {
                const int prow = qt * 16 + l16;
                pah[qt][ch] = *(const bf16x8*)(lds + PH + SW(prow, ch * 64 + lg * 16));
                pal[qt][ch] = *(const bf16x8*)(lds + PH + 4096 + SW(prow, ch * 64 + lg * 16));
            }
        #pragma unroll
        for (int et = 0; et < 4; ++et) {
            const int vrow = et * 16 + l16;
            bf16x8 vh0 = *(const bf16x8*)(lds + 16384 + SW(vrow, lg * 16));
            bf16x8 vh1 = *(const bf16x8*)(lds + 16384 + SW(vrow, 64 + lg * 16));
            bf16x8 vl0 = *(const bf16x8*)(lds + 24576 + SW(vrow, lg * 16));
            bf16x8 vl1 = *(const bf16x8*)(lds + 24576 + SW(vrow, 64 + lg * 16));
            #pragma unroll
            for (int qt = 0; qt < 2; ++qt) {
                f32x4 acc = o[qt][et];
                acc = MFMA(pah[qt][0], vh0, acc);
                acc = MFMA(pah[qt][1], vh1, acc);
                acc = MFMA(pah[qt][0], vl0, acc);
                acc = MFMA(pah[qt][1], vl1, acc);
                acc = MFMA(pal[qt][0], vh0, acc);
                acc = MFMA(pal[qt][1], vh1, acc);
                o[qt][et] = acc;
            }
        }
        __syncthreads();
    }

    // ---- epilogue: normalize, store fp32 [B,S,TD] ----
    #pragma unroll
    for (int qt = 0; qt < 2; ++qt) {
        f32x4 rn;
        rn.x = 1.0f / ls[qt].x; rn.y = 1.0f / ls[qt].y;
        rn.z = 1.0f / ls[qt].z; rn.w = 1.0f / ls[qt].w;
        #pragma unroll
        for (int et = 0; et < 4; ++et)
            #pragma unroll
            for (int r = 0; r < 4; ++r) {
                const int srow = qrow0 + qt * 16 + lg * 4 + r;
                out[((size_t)b * SS + srow) * TD + h * HD + et * 16 + l16] = o[qt][et][r] * rn[r];
            }
    }
}

extern "C" void kernel_launch(void* const* d_in, const int* in_sizes, int n_in,
                              void* d_out, int out_size, void* d_ws, size_t ws_size,
                              hipStream_t stream) {
    const float* x  = (const float*)d_in[0];
    const float* Wq = (const float*)d_in[1];
    const float* Wk = (const float*)d_in[2];
    const float* Wv = (const float*)d_in[3];
    const float* bq = (const float*)d_in[4];
    const float* bk = (const float*)d_in[5];
    const float* bv = (const float*)d_in[6];
    float* outp = (float*)d_out;

    const size_t per = (size_t)BB * NH * SS * HD;   // 8.39M floats
    float* q  = (float*)d_ws;                       // 96 MB total workspace
    float* k  = q + per;
    float* vt = k + per;                            // [pair][64][S] transposed

    proj_kernel<<<dim3(SS / 128, NH, BB), dim3(256), 0, stream>>>(
        x, Wq, Wk, Wv, bq, bk, bv, q, k, vt);
    attn_kernel<<<dim3(1024), dim3(256), 0, stream>>>(q, k, vt, outp);
}

// Round 4
// 263.196 us; speedup vs baseline: 2.3941x; 1.0060x over previous
//
#include <hip/hip_runtime.h>
#include <stdint.h>

#define NH 16
#define HD 64
#define BB 8
#define SS 1024
#define TD 1024

typedef __attribute__((ext_vector_type(8))) short bf16x8;
typedef __attribute__((ext_vector_type(4))) float f32x4;

#define MFMA(a, b, c) __builtin_amdgcn_mfma_f32_16x16x32_bf16((a), (b), (c), 0, 0, 0)
// XOR swizzle inside an 8KB [64 rows][128B] tile
#define SW(r, c) (((r) << 7) + ((c) ^ (((r) & 7) << 4)))

__device__ __forceinline__ float asf(unsigned u) { return __builtin_bit_cast(float, u); }

__device__ __forceinline__ unsigned cvtpk(float a, float b) {
    unsigned r;
    asm("v_cvt_pk_bf16_f32 %0, %1, %2" : "=v"(r) : "v"(a), "v"(b));
    return r;
}

struct HiLo { uint4 hi, lo; };
// split 8 fp32 -> 8 bf16 hi + 8 bf16 lo (lo = RTNE(x - hi))
__device__ __forceinline__ HiLo split8(float4 A, float4 B) {
    HiLo r;
    unsigned h0 = cvtpk(A.x, A.y), h1 = cvtpk(A.z, A.w);
    unsigned h2 = cvtpk(B.x, B.y), h3 = cvtpk(B.z, B.w);
    r.hi = make_uint4(h0, h1, h2, h3);
    float l0 = A.x - asf(h0 << 16), l1 = A.y - asf(h0 & 0xFFFF0000u);
    float l2 = A.z - asf(h1 << 16), l3 = A.w - asf(h1 & 0xFFFF0000u);
    float l4 = B.x - asf(h2 << 16), l5 = B.y - asf(h2 & 0xFFFF0000u);
    float l6 = B.z - asf(h3 << 16), l7 = B.w - asf(h3 & 0xFFFF0000u);
    r.lo = make_uint4(cvtpk(l0, l1), cvtpk(l2, l3), cvtpk(l4, l5), cvtpk(l6, l7));
    return r;
}

__device__ __forceinline__ void gload16(const void* g, void* l) {
    __builtin_amdgcn_global_load_lds(
        (const __attribute__((address_space(1))) unsigned int*)g,
        (__attribute__((address_space(3))) unsigned int*)l, 16, 0, 0);
}

__device__ __forceinline__ f32x4 splat4(float v) { f32x4 r = {v, v, v, v}; return r; }
__device__ __forceinline__ f32x4 vmax4(f32x4 a, f32x4 b) {
    f32x4 r; r.x = fmaxf(a.x, b.x); r.y = fmaxf(a.y, b.y);
    r.z = fmaxf(a.z, b.z); r.w = fmaxf(a.w, b.w); return r;
}

union PU { unsigned u[4]; bf16x8 v; };

// ---------------------------------------------------------------------------
// Kernel 1: per-head QKV projection (fp32 VALU GEMM).
// Outputs: q fp32 [pair][S][64] (pre-scaled 1/8); K hi/lo bf16 [pair][S][64];
// V^T hi/lo bf16 [pair][64][S].
// ---------------------------------------------------------------------------
__global__ __launch_bounds__(256) void proj_kernel(
    const float* __restrict__ x,
    const float* __restrict__ Wq, const float* __restrict__ Wk, const float* __restrict__ Wv,
    const float* __restrict__ bq, const float* __restrict__ bk, const float* __restrict__ bv,
    float* __restrict__ qo, char* __restrict__ khO, char* __restrict__ klO,
    char* __restrict__ vhO, char* __restrict__ vlO)
{
    __shared__ float Xt[64][136];   // Xt[d][s], 128 tokens
    __shared__ float Wl[64][68];    // Wl[d][e]

    const int stile = blockIdx.x;
    const int h = blockIdx.y, b = blockIdx.z;
    const int t = threadIdx.x;
    const int s0 = stile * 128;
    const int pair = b * NH + h;

    {   // stage + transpose x tile
        const int tok = t >> 1;
        const int dh = (t & 1) * 32;
        const float* src = x + ((size_t)b * SS + s0 + tok) * TD + h * HD + dh;
        #pragma unroll
        for (int i = 0; i < 8; ++i) {
            float4 v4 = *(const float4*)(src + i * 4);
            Xt[dh + i * 4 + 0][tok] = v4.x;
            Xt[dh + i * 4 + 1][tok] = v4.y;
            Xt[dh + i * 4 + 2][tok] = v4.z;
            Xt[dh + i * 4 + 3][tok] = v4.w;
        }
    }

    const float* Ws[3] = {Wq, Wk, Wv};
    const float* bs[3] = {bq, bk, bv};

    #pragma unroll 1
    for (int tz = 0; tz < 3; ++tz) {
        __syncthreads();
        {
            const int d = t >> 2, c0 = (t & 3) * 16;
            const float* src = Ws[tz] + ((size_t)h * HD + d) * HD + c0;
            #pragma unroll
            for (int i = 0; i < 4; ++i)
                *(float4*)(&Wl[d][c0 + i * 4]) = *(const float4*)(src + i * 4);
        }
        __syncthreads();

        const bool vmap = (tz == 2);
        const int sg = vmap ? (t & 15) : (t >> 4);
        const int eg = vmap ? (t >> 4) : (t & 15);
        const int e0 = eg * 4;
        const int sA = vmap ? sg * 4 : sg * 8;
        const int sB = vmap ? 64 + sg * 4 : sg * 8 + 4;

        float acc[8][4] = {};
        #pragma unroll 4
        for (int d = 0; d < 64; ++d) {
            const float4 x0 = *(const float4*)(&Xt[d][sA]);
            const float4 x1 = *(const float4*)(&Xt[d][sB]);
            const float4 wv = *(const float4*)(&Wl[d][e0]);
            const float xs[8] = {x0.x, x0.y, x0.z, x0.w, x1.x, x1.y, x1.z, x1.w};
            const float ww[4] = {wv.x, wv.y, wv.z, wv.w};
            #pragma unroll
            for (int i = 0; i < 8; ++i)
                #pragma unroll
                for (int j = 0; j < 4; ++j)
                    acc[i][j] += xs[i] * ww[j];
        }

        if (tz == 0) {
            const float4 bb = *(const float4*)(bs[0] + h * HD + e0);
            float* dst = qo + ((size_t)pair * SS + s0 + sg * 8) * HD + e0;
            #pragma unroll
            for (int i = 0; i < 8; ++i) {
                float4 o4 = {(acc[i][0] + bb.x) * 0.125f, (acc[i][1] + bb.y) * 0.125f,
                             (acc[i][2] + bb.z) * 0.125f, (acc[i][3] + bb.w) * 0.125f};
                *(float4*)(dst + (size_t)i * HD) = o4;
            }
        } else if (tz == 1) {
            const float4 bb = *(const float4*)(bs[1] + h * HD + e0);
            char* dh = khO + (((size_t)pair * SS + s0 + sg * 8) * HD + e0) * 2;
            char* dl = klO + (((size_t)pair * SS + s0 + sg * 8) * HD + e0) * 2;
            #pragma unroll
            for (int i = 0; i < 8; ++i) {
                float a0 = acc[i][0] + bb.x, a1 = acc[i][1] + bb.y;
                float a2 = acc[i][2] + bb.z, a3 = acc[i][3] + bb.w;
                unsigned h0 = cvtpk(a0, a1), h1 = cvtpk(a2, a3);
                uint2 hv = {h0, h1};
                *(uint2*)(dh + i * 128) = hv;
                float r0 = a0 - asf(h0 << 16), r1 = a1 - asf(h0 & 0xFFFF0000u);
                float r2 = a2 - asf(h1 << 16), r3 = a3 - asf(h1 & 0xFFFF0000u);
                uint2 lv = {cvtpk(r0, r1), cvtpk(r2, r3)};
                *(uint2*)(dl + i * 128) = lv;
            }
        } else {
            #pragma unroll
            for (int j = 0; j < 4; ++j) {
                const float bbv = bs[2][h * HD + e0 + j];
                char* dh = vhO + (((size_t)pair * HD + e0 + j) * SS + s0) * 2;
                char* dl = vlO + (((size_t)pair * HD + e0 + j) * SS + s0) * 2;
                float t0 = acc[0][j] + bbv, t1 = acc[1][j] + bbv;
                float t2 = acc[2][j] + bbv, t3 = acc[3][j] + bbv;
                float t4 = acc[4][j] + bbv, t5 = acc[5][j] + bbv;
                float t6 = acc[6][j] + bbv, t7 = acc[7][j] + bbv;
                unsigned h0 = cvtpk(t0, t1), h1 = cvtpk(t2, t3);
                unsigned h2 = cvtpk(t4, t5), h3 = cvtpk(t6, t7);
                uint2 ha = {h0, h1}, hb = {h2, h3};
                *(uint2*)(dh + sA * 2) = ha;
                *(uint2*)(dh + sB * 2) = hb;
                float r0 = t0 - asf(h0 << 16), r1 = t1 - asf(h0 & 0xFFFF0000u);
                float r2 = t2 - asf(h1 << 16), r3 = t3 - asf(h1 & 0xFFFF0000u);
                float r4 = t4 - asf(h2 << 16), r5 = t5 - asf(h2 & 0xFFFF0000u);
                float r6 = t6 - asf(h3 << 16), r7 = t7 - asf(h3 & 0xFFFF0000u);
                uint2 la = {cvtpk(r0, r1), cvtpk(r2, r3)};
                uint2 lb = {cvtpk(r4, r5), cvtpk(r6, r7)};
                *(uint2*)(dl + sA * 2) = la;
                *(uint2*)(dl + sB * 2) = lb;
            }
        }
    }
}

// ---------------------------------------------------------------------------
// Kernel 2: flash attention, swapped-QK^T bf16 MFMA hi/lo, gload_lds staging.
// QBLK=128 (4 waves x 32 q), KVBLK=64, double-buffered K/V.
// LDS 80KB: buf0 [Kh 8K|Kl 8K|Vh 8K|Vl 8K] | buf1 same | per-wave P 4K x4
// ---------------------------------------------------------------------------
__global__ __launch_bounds__(256) void attn_kernel(
    const float* __restrict__ qf,
    const char* __restrict__ khG, const char* __restrict__ klG,
    const char* __restrict__ vhG, const char* __restrict__ vlG,
    float* __restrict__ out)
{
    __shared__ __align__(16) char lds[81920];

    // XCD-bijective swizzle: 1024 = 8 XCDs x 128; q-block fastest -> KV L2 reuse
    const int p = blockIdx.x;
    const int id = (p & 7) * 128 + (p >> 3);
    const int st = id & 7;
    const int pr = id >> 3;
    const int h = pr & (NH - 1);
    const int b = pr >> 4;

    const int t = threadIdx.x;
    const int w = t >> 6;
    const int l = t & 63;
    const int l16 = l & 15;
    const int lg = l >> 4;

    // ---- Q fragments (B-operand), hi/lo split, once ----
    bf16x8 qh[2][2], ql[2][2];
    #pragma unroll
    for (int qt = 0; qt < 2; ++qt)
        #pragma unroll
        for (int ch = 0; ch < 2; ++ch) {
            const float* src = qf + (size_t)pr * (SS * HD)
                + (size_t)(st * 128 + w * 32 + qt * 16 + l16) * HD + ch * 32 + lg * 8;
            float4 A = *(const float4*)src;
            float4 B = *(const float4*)(src + 4);
            HiLo s8 = split8(A, B);
            qh[qt][ch] = __builtin_bit_cast(bf16x8, s8.hi);
            ql[qt][ch] = __builtin_bit_cast(bf16x8, s8.lo);
        }

    // per-lane pre-XORed source offsets (linear LDS dest -> swizzled image)
    int koff[2], voff[2];
    #pragma unroll
    for (int j = 0; j < 2; ++j) {
        const int o = w * 2048 + j * 1024 + l * 16;
        const int r = o >> 7;
        const int c = (o & 127) ^ ((r & 7) << 4);
        koff[j] = r * 128 + c;
        voff[j] = r * 2048 + c;
    }
    const char* khB = khG + (size_t)pr * 131072;
    const char* klB = klG + (size_t)pr * 131072;
    const char* vhB = vhG + (size_t)pr * 131072;
    const char* vlB = vlG + (size_t)pr * 131072;

    auto stage = [&](int kt, int base) {
        #pragma unroll
        for (int j = 0; j < 2; ++j) {
            char* ld = lds + base + w * 2048 + j * 1024;
            gload16(khB + (size_t)kt * 8192 + koff[j], ld);
            gload16(klB + (size_t)kt * 8192 + koff[j], ld + 8192);
            gload16(vhB + (size_t)kt * 128 + voff[j], ld + 16384);
            gload16(vlB + (size_t)kt * 128 + voff[j], ld + 24576);
        }
    };

    float m[2] = {-3e38f, -3e38f}, lsum[2] = {0.f, 0.f};
    f32x4 o[2][4];
    #pragma unroll
    for (int qt = 0; qt < 2; ++qt)
        #pragma unroll
        for (int et = 0; et < 4; ++et) o[qt][et] = splat4(0.f);

    const int PB = 65536 + w * 4096;   // per-wave P pairs: hi 2K, lo 2K

    stage(0, 0);

    for (int kt = 0; kt < 16; ++kt) {
        __syncthreads();               // drains gload_lds; buffers ready
        const int X = (kt & 1) ? 32768 : 0;
        if (kt < 15) stage(kt + 1, 32768 - X);

        // ---- St = K Q^T : C[k][q] (3-pass hi/lo) ----
        f32x4 s_[2][4];
        #pragma unroll
        for (int jt = 0; jt < 4; ++jt) {
            const int krow = jt * 16 + l16;
            bf16x8 kh0 = *(const bf16x8*)(lds + X + SW(krow, lg * 16));
            bf16x8 kh1 = *(const bf16x8*)(lds + X + SW(krow, 64 + lg * 16));
            bf16x8 kl0 = *(const bf16x8*)(lds + X + 8192 + SW(krow, lg * 16));
            bf16x8 kl1 = *(const bf16x8*)(lds + X + 8192 + SW(krow, 64 + lg * 16));
            #pragma unroll
            for (int qt = 0; qt < 2; ++qt) {
                f32x4 acc = splat4(0.f);
                acc = MFMA(kh0, qh[qt][0], acc);
                acc = MFMA(kh1, qh[qt][1], acc);
                acc = MFMA(kl0, qh[qt][0], acc);
                acc = MFMA(kl1, qh[qt][1], acc);
                acc = MFMA(kh0, ql[qt][0], acc);
                acc = MFMA(kh1, ql[qt][1], acc);
                s_[qt][jt] = acc;
            }
        }

        // ---- online softmax: lane owns 16 k of q = qt*16+l16 ----
        #pragma unroll
        for (int qt = 0; qt < 2; ++qt) {
            f32x4 m4 = vmax4(vmax4(s_[qt][0], s_[qt][1]), vmax4(s_[qt][2], s_[qt][3]));
            float mm = fmaxf(fmaxf(m4.x, m4.y), fmaxf(m4.z, m4.w));
            mm = fmaxf(mm, __shfl_xor(mm, 16));
            mm = fmaxf(mm, __shfl_xor(mm, 32));
            const float nm = fmaxf(m[qt], mm);
            const float sc = __expf(m[qt] - nm);
            m[qt] = nm;
            f32x4 ps = splat4(0.f);
            #pragma unroll
            for (int jt = 0; jt < 4; ++jt) {
                f32x4 pv;
                pv.x = __expf(s_[qt][jt].x - nm);
                pv.y = __expf(s_[qt][jt].y - nm);
                pv.z = __expf(s_[qt][jt].z - nm);
                pv.w = __expf(s_[qt][jt].w - nm);
                s_[qt][jt] = pv;
                ps += pv;
            }
            float pss = ps.x + ps.y + ps.z + ps.w;
            pss += __shfl_xor(pss, 16);
            pss += __shfl_xor(pss, 32);
            lsum[qt] = lsum[qt] * sc + pss;
            #pragma unroll
            for (int et = 0; et < 4; ++et) o[qt][et] *= sc;
        }

        // ---- O^T += V^T P, two k-halves (3-pass hi/lo) ----
        #pragma unroll
        for (int hf = 0; hf < 2; ++hf) {
            // pack P pairs (along k) into per-wave LDS
            #pragma unroll
            for (int qt = 0; qt < 2; ++qt)
                #pragma unroll
                for (int jl = 0; jl < 2; ++jl) {
                    f32x4 P4 = s_[qt][hf * 2 + jl];
                    unsigned u0 = cvtpk(P4.x, P4.y);
                    unsigned u1 = cvtpk(P4.z, P4.w);
                    float r0 = P4.x - asf(u0 << 16), r1 = P4.y - asf(u0 & 0xFFFF0000u);
                    float r2 = P4.z - asf(u1 << 16), r3 = P4.w - asf(u1 & 0xFFFF0000u);
                    unsigned v0 = cvtpk(r0, r1), v1 = cvtpk(r2, r3);
                    const int pr0 = jl * 8 + lg * 2;
                    const int cb = (qt * 16 + l16) * 4;
                    *(unsigned*)(lds + PB + pr0 * 128 + (cb ^ ((pr0 & 7) << 4))) = u0;
                    *(unsigned*)(lds + PB + (pr0 + 1) * 128 + (cb ^ (((pr0 + 1) & 7) << 4))) = u1;
                    *(unsigned*)(lds + PB + 2048 + pr0 * 128 + (cb ^ ((pr0 & 7) << 4))) = v0;
                    *(unsigned*)(lds + PB + 2048 + (pr0 + 1) * 128 + (cb ^ (((pr0 + 1) & 7) << 4))) = v1;
                }
            // read P B-fragments (in-order wave LDS: no barrier needed)
            bf16x8 pH[2], pL[2];
            #pragma unroll
            for (int qt = 0; qt < 2; ++qt) {
                PU ph, pl;
                #pragma unroll
                for (int v = 0; v < 4; ++v) {
                    const int prr = lg * 4 + v;
                    const int a = prr * 128 + (((qt * 16 + l16) * 4) ^ ((prr & 7) << 4));
                    ph.u[v] = *(const unsigned*)(lds + PB + a);
                    pl.u[v] = *(const unsigned*)(lds + PB + 2048 + a);
                }
                pH[qt] = ph.v;
                pL[qt] = pl.v;
            }
            // V^T fragments + MFMA
            #pragma unroll
            for (int et = 0; et < 4; ++et) {
                const int vrow = et * 16 + l16;
                bf16x8 vh_ = *(const bf16x8*)(lds + X + 16384 + SW(vrow, hf * 64 + lg * 16));
                bf16x8 vl_ = *(const bf16x8*)(lds + X + 24576 + SW(vrow, hf * 64 + lg * 16));
                #pragma unroll
                for (int qt = 0; qt < 2; ++qt) {
                    f32x4 a2 = o[qt][et];
                    a2 = MFMA(vh_, pH[qt], a2);
                    a2 = MFMA(vh_, pL[qt], a2);
                    a2 = MFMA(vl_, pH[qt], a2);
                    o[qt][et] = a2;
                }
            }
        }
    }

    // ---- epilogue: O^T regs -> out[B,S,TD]; e = et*16+lg*4+r, q = qt*16+l16 ----
    #pragma unroll
    for (int qt = 0; qt < 2; ++qt) {
        const float inv = 1.0f / lsum[qt];
        const size_t row = (size_t)b * SS + st * 128 + w * 32 + qt * 16 + l16;
        #pragma unroll
        for (int et = 0; et < 4; ++et) {
            float4 o4 = {o[qt][et].x * inv, o[qt][et].y * inv,
                         o[qt][et].z * inv, o[qt][et].w * inv};
            *(float4*)(out + row * TD + h * HD + et * 16 + lg * 4) = o4;
        }
    }
}

extern "C" void kernel_launch(void* const* d_in, const int* in_sizes, int n_in,
                              void* d_out, int out_size, void* d_ws, size_t ws_size,
                              hipStream_t stream) {
    const float* x  = (const float*)d_in[0];
    const float* Wq = (const float*)d_in[1];
    const float* Wk = (const float*)d_in[2];
    const float* Wv = (const float*)d_in[3];
    const float* bq = (const float*)d_in[4];
    const float* bk = (const float*)d_in[5];
    const float* bv = (const float*)d_in[6];
    float* outp = (float*)d_out;

    char* base = (char*)d_ws;                    // 96 MiB total
    float* q  = (float*)base;                    // 32 MiB fp32 [pair][S][64]
    char* kh = base + (size_t)32 * 1024 * 1024;  // 16 MiB bf16 [pair][S][64]
    char* kl = base + (size_t)48 * 1024 * 1024;
    char* vh = base + (size_t)64 * 1024 * 1024;  // 16 MiB bf16 [pair][64][S]
    char* vl = base + (size_t)80 * 1024 * 1024;

    proj_kernel<<<dim3(SS / 128, NH, BB), dim3(256), 0, stream>>>(
        x, Wq, Wk, Wv, bq, bk, bv, q, kh, kl, vh, vl);
    attn_kernel<<<dim3(1024), dim3(256), 0, stream>>>(q, kh, kl, vh, vl, outp);
}

// Round 6
// 147.897 us; speedup vs baseline: 4.2605x; 1.7796x over previous
//
#include <hip/hip_runtime.h>
#include <stdint.h>

#define NH 16
#define HD 64
#define BB 8
#define SS 1024
#define TD 1024

typedef _Float16 f16;
typedef __attribute__((ext_vector_type(8))) f16 f16x8;
typedef __attribute__((ext_vector_type(16))) float f32x16;

#define MFMA32(a, b, c) __builtin_amdgcn_mfma_f32_32x32x16_f16((a), (b), (c), 0, 0, 0)
// XOR swizzle inside a [rows][128B] tile (8-row stripes, 16B slots)
#define SW(r, c) (((r) << 7) + ((c) ^ (((r) & 7) << 4)))

__device__ __forceinline__ unsigned pkrtz(float a, float b) {
    auto r = __builtin_amdgcn_cvt_pkrtz(a, b);
    return __builtin_bit_cast(unsigned, r);
}
__device__ __forceinline__ unsigned h16(float a) {
    f16 h = (f16)a;   // RTNE v_cvt_f16_f32
    return (unsigned)__builtin_bit_cast(unsigned short, h);
}
__device__ __forceinline__ unsigned pk_rtne(float a, float b) {
    return h16(a) | (h16(b) << 16);
}
__device__ __forceinline__ void gload16(const void* g, void* l) {
    __builtin_amdgcn_global_load_lds(
        (const __attribute__((address_space(1))) unsigned int*)g,
        (__attribute__((address_space(3))) unsigned int*)l, 16, 0, 0);
}

// ---------------------------------------------------------------------------
// Kernel 1: QKV projection via fp16 MFMA. Per block: (b, h, 128-token tile).
// Outputs fp16: q [pair][S][64] pre-scaled by 0.125*log2(e); k [pair][S][64];
// v TRANSPOSED [pair][64][S].
// LDS 40KB: X [128][128B] @0 | Wq^T @16K | Wk^T @24K | Wv^T @32K (all [64][128B], SW)
// ---------------------------------------------------------------------------
__global__ __launch_bounds__(256) void proj_kernel(
    const float* __restrict__ x,
    const float* __restrict__ Wq, const float* __restrict__ Wk, const float* __restrict__ Wv,
    const float* __restrict__ bq, const float* __restrict__ bk, const float* __restrict__ bv,
    f16* __restrict__ qo, f16* __restrict__ ko, f16* __restrict__ vo)
{
    __shared__ __align__(16) char lds[40960];
    const int stile = blockIdx.x, h = blockIdx.y, b = blockIdx.z;
    const int t = threadIdx.x;
    const int s0 = stile * 128;
    const int pair = b * NH + h;

    {   // stage X tile -> fp16, swizzled [s][d]
        const int row = t >> 1, half = t & 1;
        const float* src = x + ((size_t)b * SS + s0 + row) * TD + h * HD + half * 32;
        #pragma unroll
        for (int i = 0; i < 8; ++i) {
            float4 v4 = *(const float4*)(src + i * 4);
            const int cb = half * 64 + i * 8;
            *(unsigned*)(lds + SW(row, cb))     = pk_rtne(v4.x, v4.y);
            *(unsigned*)(lds + SW(row, cb + 4)) = pk_rtne(v4.z, v4.w);
        }
    }
    {   // stage W^T [e][d] fp16, swizzled (transposed read: thread owns e)
        const int e = t & 63, dg = t >> 6;
        const float* Ws[3] = {Wq, Wk, Wv};
        #pragma unroll
        for (int z = 0; z < 3; ++z) {
            const float* src = Ws[z] + (size_t)h * 4096 + (size_t)dg * 16 * 64 + e;
            char* base = lds + 16384 + z * 8192;
            #pragma unroll
            for (int j = 0; j < 8; ++j) {
                const float a0 = src[(2 * j) * 64], a1 = src[(2 * j + 1) * 64];
                const int cb = dg * 32 + j * 4;
                *(unsigned*)(base + SW(e, cb)) = pk_rtne(a0, a1);
            }
        }
    }
    __syncthreads();

    const int w = t >> 6, l = t & 63, l31 = l & 31, hi = l >> 5;
    const float* bs[3] = {bq, bk, bv};

    // X A-frags for rows w*32+l31 (q,k GEMMs)
    f16x8 xa[4];
    #pragma unroll
    for (int c = 0; c < 4; ++c)
        xa[c] = *(const f16x8*)(lds + SW(w * 32 + l31, c * 32 + hi * 16));

    #pragma unroll
    for (int z = 0; z < 2; ++z) {   // q, k: C[s][e]
        const char* wb = lds + 16384 + z * 8192;
        f32x16 acc[2] = {};
        #pragma unroll
        for (int nt = 0; nt < 2; ++nt)
            #pragma unroll
            for (int c = 0; c < 4; ++c) {
                f16x8 wf = *(const f16x8*)(wb + SW(nt * 32 + l31, c * 32 + hi * 16));
                acc[nt] = MFMA32(xa[c], wf, acc[nt]);
            }
        const float scl = (z == 0) ? 0.125f * 1.44269504088896f : 1.0f;
        f16* dst = (z == 0) ? qo : ko;
        #pragma unroll
        for (int nt = 0; nt < 2; ++nt) {
            const int e = nt * 32 + l31;
            const float bb = bs[z][h * 64 + e];
            #pragma unroll
            for (int r = 0; r < 16; ++r) {
                const int sl = w * 32 + (r & 3) + 8 * (r >> 2) + 4 * hi;
                dst[(size_t)pair * 65536 + (size_t)(s0 + sl) * 64 + e] =
                    (f16)((acc[nt][r] + bb) * scl);
            }
        }
    }
    {   // v swapped: C[e][s] -> V^T [pair][64][S]
        const char* wb = lds + 16384 + 2 * 8192;
        const int mt = w & 1, ng = w >> 1;
        f16x8 wv[4];
        #pragma unroll
        for (int c = 0; c < 4; ++c)
            wv[c] = *(const f16x8*)(wb + SW(mt * 32 + l31, c * 32 + hi * 16));
        float bvv[16];
        #pragma unroll
        for (int r = 0; r < 16; ++r)
            bvv[r] = bs[2][h * 64 + mt * 32 + (r & 3) + 8 * (r >> 2) + 4 * hi];
        f32x16 acc[2] = {};
        #pragma unroll
        for (int j = 0; j < 2; ++j) {
            const int srow = (ng * 2 + j) * 32 + l31;
            #pragma unroll
            for (int c = 0; c < 4; ++c) {
                f16x8 xf = *(const f16x8*)(lds + SW(srow, c * 32 + hi * 16));
                acc[j] = MFMA32(wv[c], xf, acc[j]);
            }
        }
        #pragma unroll
        for (int j = 0; j < 2; ++j) {
            const int sl = (ng * 2 + j) * 32 + l31;
            #pragma unroll
            for (int r = 0; r < 16; ++r) {
                const int e = mt * 32 + (r & 3) + 8 * (r >> 2) + 4 * hi;
                vo[(size_t)pair * 65536 + (size_t)e * 1024 + s0 + sl] =
                    (f16)(acc[j][r] + bvv[r]);
            }
        }
    }
}

// ---------------------------------------------------------------------------
// Kernel 2: flash attention, fp16 single-pass 32x32x16 MFMA.
// QBLK=128 (4 waves x 32 q), KVBLK=64, double-buffered K/V via gload_lds.
// P->PV fragment redistribution fully in-register (cvt_pkrtz + permlane32_swap).
// LDS 32KB: buf0 [K 8K | V^T 8K] | buf1 same.
// ---------------------------------------------------------------------------
__global__ __launch_bounds__(256, 4) void attn_kernel(
    const f16* __restrict__ qf, const f16* __restrict__ kf,
    const f16* __restrict__ vt, float* __restrict__ out)
{
    __shared__ __align__(16) char lds[32768];

    // XCD-bijective swizzle: 1024 = 8 XCDs x 128; q-block fastest -> KV L2 reuse
    const int p = blockIdx.x;
    const int id = (p & 7) * 128 + (p >> 3);
    const int st = id & 7;
    const int pr = id >> 3;
    const int h = pr & (NH - 1), b = pr >> 4;

    const int t = threadIdx.x, w = t >> 6, l = t & 63, l31 = l & 31, hi = l >> 5;

    // Q B-frags (once): B[n=q][k=d], q = l31 within wave's 32 rows
    f16x8 qfr[4];
    {
        const char* qp = (const char*)(qf + (size_t)pr * 65536)
                       + (size_t)(st * 128 + w * 32 + l31) * 128;
        #pragma unroll
        for (int c = 0; c < 4; ++c)
            qfr[c] = *(const f16x8*)(qp + c * 32 + hi * 16);
    }

    // staging: pre-XORed per-lane global sources, linear LDS dest
    int koff[2], voff[2];
    #pragma unroll
    for (int j = 0; j < 2; ++j) {
        const int o = j * 4096 + w * 1024 + l * 16;
        const int r = o >> 7, c = o & 127;
        const int cs = c ^ ((r & 7) << 4);
        koff[j] = r * 128 + cs;
        voff[j] = r * 2048 + cs;
    }
    const char* kB = (const char*)(kf + (size_t)pr * 65536);
    const char* vB = (const char*)(vt + (size_t)pr * 65536);

    auto stage = [&](int kt, int base) {
        #pragma unroll
        for (int j = 0; j < 2; ++j) {
            char* ld = lds + base + j * 4096 + w * 1024;   // wave-uniform; HW adds lane*16
            gload16(kB + (size_t)kt * 8192 + koff[j], ld);
            gload16(vB + (size_t)kt * 128 + voff[j], ld + 8192);
        }
    };

    float m = -3e38f, lsum = 0.f;
    f32x16 o_[2] = {};

    stage(0, 0);

    for (int kt = 0; kt < 16; ++kt) {
        __syncthreads();                       // drains gload_lds; buffer ready
        const int X = (kt & 1) ? 16384 : 0;
        if (kt < 15) stage(kt + 1, 16384 - X);

        // ---- S^T = K Q^T : C[k][q], 2 S-tiles of 32 k ----
        f32x16 s_[2] = {};
        #pragma unroll
        for (int jt = 0; jt < 2; ++jt)
            #pragma unroll
            for (int c = 0; c < 4; ++c) {
                f16x8 kfr = *(const f16x8*)(lds + X + SW(jt * 32 + l31, c * 32 + hi * 16));
                s_[jt] = MFMA32(kfr, qfr[c], s_[jt]);
            }

        // ---- online softmax (log2 domain; q pre-scaled by log2e/8) ----
        float mm = s_[0][0];
        #pragma unroll
        for (int i = 1; i < 16; ++i) mm = fmaxf(mm, s_[0][i]);
        #pragma unroll
        for (int i = 0; i < 16; ++i) mm = fmaxf(mm, s_[1][i]);
        mm = fmaxf(mm, __shfl_xor(mm, 32));
        const float nm = fmaxf(m, mm);
        const float sc = __builtin_amdgcn_exp2f(m - nm);
        m = nm;
        float ps = 0.f;
        #pragma unroll
        for (int jt = 0; jt < 2; ++jt)
            #pragma unroll
            for (int i = 0; i < 16; ++i) {
                const float e = __builtin_amdgcn_exp2f(s_[jt][i] - nm);
                s_[jt][i] = e;
                ps += e;
            }
        ps += __shfl_xor(ps, 32);
        lsum = lsum * sc + ps;
        #pragma unroll
        for (int i = 0; i < 16; ++i) { o_[0][i] *= sc; o_[1][i] *= sc; }

        // ---- P pack (in-register) + O^T += V^T P ----
        #pragma unroll
        for (int jt = 0; jt < 2; ++jt) {
            unsigned u[8];
            #pragma unroll
            for (int a = 0; a < 4; ++a) {
                u[2 * a]     = pkrtz(s_[jt][4 * a],     s_[jt][4 * a + 1]);
                u[2 * a + 1] = pkrtz(s_[jt][4 * a + 2], s_[jt][4 * a + 3]);
            }
            // lane-half exchange: one swap fills two output words (T12)
            {
                auto r0 = __builtin_amdgcn_permlane32_swap(u[0], u[2], false, false);
                u[0] = r0[0]; u[2] = r0[1];
                auto r1 = __builtin_amdgcn_permlane32_swap(u[1], u[3], false, false);
                u[1] = r1[0]; u[3] = r1[1];
                auto r2 = __builtin_amdgcn_permlane32_swap(u[4], u[6], false, false);
                u[4] = r2[0]; u[6] = r2[1];
                auto r3 = __builtin_amdgcn_permlane32_swap(u[5], u[7], false, false);
                u[5] = r3[0]; u[7] = r3[1];
            }
            #pragma unroll
            for (int cl = 0; cl < 2; ++cl) {
                uint4 pu = {u[cl * 4], u[cl * 4 + 1], u[cl * 4 + 2], u[cl * 4 + 3]};
                f16x8 pf = __builtin_bit_cast(f16x8, pu);
                const int cv = jt * 2 + cl;
                #pragma unroll
                for (int mt = 0; mt < 2; ++mt) {
                    f16x8 vf = *(const f16x8*)(lds + X + 8192 + SW(mt * 32 + l31, cv * 32 + hi * 16));
                    o_[mt] = MFMA32(vf, pf, o_[mt]);
                }
            }
        }
    }

    // ---- epilogue: O^T[e][q] regs -> out[B,S,TD] fp32, float4 stores ----
    const float inv = 1.0f / lsum;
    const size_t row = (size_t)b * SS + st * 128 + w * 32 + l31;
    float* op = out + row * TD + h * 64;
    #pragma unroll
    for (int mt = 0; mt < 2; ++mt)
        #pragma unroll
        for (int g = 0; g < 4; ++g) {
            const int e0 = mt * 32 + 8 * g + 4 * hi;
            float4 o4 = {o_[mt][4 * g] * inv, o_[mt][4 * g + 1] * inv,
                         o_[mt][4 * g + 2] * inv, o_[mt][4 * g + 3] * inv};
            *(float4*)(op + e0) = o4;
        }
}

extern "C" void kernel_launch(void* const* d_in, const int* in_sizes, int n_in,
                              void* d_out, int out_size, void* d_ws, size_t ws_size,
                              hipStream_t stream) {
    const float* x  = (const float*)d_in[0];
    const float* Wq = (const float*)d_in[1];
    const float* Wk = (const float*)d_in[2];
    const float* Wv = (const float*)d_in[3];
    const float* bq = (const float*)d_in[4];
    const float* bk = (const float*)d_in[5];
    const float* bv = (const float*)d_in[6];
    float* outp = (float*)d_out;

    const size_t per = (size_t)BB * NH * SS * HD;   // 8.39M f16 = 16 MiB each
    f16* q  = (f16*)d_ws;
    f16* k  = q + per;
    f16* vt = k + per;                              // [pair][64][S]

    proj_kernel<<<dim3(SS / 128, NH, BB), dim3(256), 0, stream>>>(
        x, Wq, Wk, Wv, bq, bk, bv, q, k, vt);
    attn_kernel<<<dim3(1024), dim3(256), 0, stream>>>(q, k, vt, outp);
}